// Round 2
// baseline (1298.319 us; speedup 1.0000x reference)
//
#include <hip/hip_runtime.h>
#include <hip/hip_bf16.h>

// BinarizedLinear: act[d,o] = sum_i W[d,o,i] * x[d,i];  out[d,o] = act > bias[d,o]
// W: [D][OUT][IN] fp32 of 0/1   (1.074 GB -- the whole cost; read once, coalesced)
// x: [D][IN] bool               (byte / int32 / float32 storage -- detected on device)
// bias: [D][OUT] fp32
// out: [D][OUT] as float 1.0/0.0 (reference returns bool)

#define NDIR 64
#define NOUT 2048
#define NIN  2048

typedef float f4 __attribute__((ext_vector_type(4)));

__global__ __launch_bounds__(256) void binlin_kernel(
    const float* __restrict__ W,
    const unsigned char* __restrict__ X,
    const float* __restrict__ B,
    float* __restrict__ out)
{
    const int lane = threadIdx.x & 63;
    const int wave = threadIdx.x >> 6;                 // 4 waves/block, 1 row/wave
    const int row  = blockIdx.x * 4 + wave;            // [0, NDIR*NOUT)
    const int d    = row >> 11;                        // row / NOUT  (OUT = 2048)

    // --- storage-format probe for X (deterministic, wave-uniform) ---
    // float32 storage: words are 0x00000000 / 0x3F800000 -> some word == 0x3F800000
    //   (impossible for 0/1-byte or 0/1-int words; absent w.p. 2^-64 under float).
    // numpy-bool bytes: 4 packed 0/1 bytes per word -> some word > 1 w.p. 1 - 8^-64.
    // int32 storage: every word is exactly 0 or 1.
    const unsigned int probe = ((const unsigned int*)X)[lane];   // first 256 B, in-bounds in all layouts
    const bool x_is_float = (__ballot(probe == 0x3F800000u) != 0ull);
    const bool x_is_bytes = !x_is_float && (__ballot(probe > 1u) != 0ull);

    const f4* w4 = (const f4*)(W + (size_t)row * NIN); // 8 KB row, lane-coalesced float4

    float acc = 0.0f;
    if (x_is_float) {
        const f4* xf = (const f4*)X + (size_t)d * (NIN / 4);
        #pragma unroll
        for (int j = 0; j < 8; ++j) {
            const int idx = j * 64 + lane;             // coalesced across the wave
            const f4 w = w4[idx];
            const f4 xv = xf[idx];                     // L1/L2-hot: row reused 2048x
            acc += (xv.x != 0.0f) ? w.x : 0.0f;
            acc += (xv.y != 0.0f) ? w.y : 0.0f;
            acc += (xv.z != 0.0f) ? w.z : 0.0f;
            acc += (xv.w != 0.0f) ? w.w : 0.0f;
        }
    } else if (x_is_bytes) {
        const unsigned int* x4 = (const unsigned int*)(X + (size_t)d * NIN);
        #pragma unroll
        for (int j = 0; j < 8; ++j) {
            const int idx = j * 64 + lane;
            const f4 w = w4[idx];
            const unsigned int xb = x4[idx];           // 4 bool bytes
            acc += (xb & 0x000000ffu) ? w.x : 0.0f;
            acc += (xb & 0x0000ff00u) ? w.y : 0.0f;
            acc += (xb & 0x00ff0000u) ? w.z : 0.0f;
            acc += (xb & 0xff000000u) ? w.w : 0.0f;
        }
    } else {
        const int* xi = (const int*)X + (size_t)d * NIN;
        #pragma unroll
        for (int j = 0; j < 8; ++j) {
            const int idx = j * 64 + lane;
            const f4 w = w4[idx];
            acc += xi[idx * 4 + 0] ? w.x : 0.0f;
            acc += xi[idx * 4 + 1] ? w.y : 0.0f;
            acc += xi[idx * 4 + 2] ? w.z : 0.0f;
            acc += xi[idx * 4 + 3] ? w.w : 0.0f;
        }
    }

    // wave-64 reduction; sums are exact small integers in fp32 -> order-independent
    #pragma unroll
    for (int off = 32; off > 0; off >>= 1)
        acc += __shfl_down(acc, off, 64);

    if (lane == 0)
        out[row] = (acc > B[row]) ? 1.0f : 0.0f;
}

extern "C" void kernel_launch(void* const* d_in, const int* in_sizes, int n_in,
                              void* d_out, int out_size, void* d_ws, size_t ws_size,
                              hipStream_t stream) {
    const float*         W = (const float*)d_in[0];
    const unsigned char* X = (const unsigned char*)d_in[1];
    const float*         B = (const float*)d_in[2];
    float*               O = (float*)d_out;

    const int rows = NDIR * NOUT;                      // 131072
    binlin_kernel<<<dim3(rows / 4), dim3(256), 0, stream>>>(W, X, B, O);
}

// Round 4
// 1264.226 us; speedup vs baseline: 1.0270x; 1.0270x over previous
//
#include <hip/hip_runtime.h>

// BinarizedLinear: act[d,o] = sum_i W[d,o,i] * x[d,i];  out[d,o] = act > bias[d,o]
// W: [D][OUT][IN] fp32 of 0/1   (1.074 GB -- the whole cost; read once, coalesced, nontemporal)
// x: [D][IN] bool               (byte / int32 / float32 storage -- detected on device)
// bias: [D][OUT] fp32
// out: [D][OUT] as float 1.0/0.0 (reference returns bool)
//
// Structure: 1 wave = 1 output row (8 KB of W). All 8 dwordx4 W loads issued
// up front (8 KB MLP/wave) as nontemporal; x gates loaded while W is in
// flight; gated adds afterwards. Sums are exact small integers in fp32, so
// any reduction order is bit-exact vs the reference.

#define NDIR 64
#define NOUT 2048
#define NIN  2048

typedef float f4 __attribute__((ext_vector_type(4)));

__global__ __launch_bounds__(256) void binlin_kernel(
    const float* __restrict__ W,
    const unsigned char* __restrict__ X,
    const float* __restrict__ B,
    float* __restrict__ out)
{
    const int lane = threadIdx.x & 63;
    const int wave = threadIdx.x >> 6;                 // 4 waves/block, 1 row/wave
    const int row  = blockIdx.x * 4 + wave;            // [0, NDIR*NOUT)
    const int d    = row >> 11;                        // row / NOUT  (OUT = 2048)

    // --- storage-format probe for X (deterministic, wave-uniform) ---
    // float32: some word == 0x3F800000 (absent w.p. 2^-64).
    // bool bytes: some word > 1 (absent w.p. 8^-64).  int32: all words in {0,1}.
    const unsigned int probe = ((const unsigned int*)X)[lane];   // 256 B, in-bounds in all layouts
    const bool x_is_float = (__ballot(probe == 0x3F800000u) != 0ull);
    const bool x_is_bytes = !x_is_float && (__ballot(probe > 1u) != 0ull);

    const f4* w4 = (const f4*)(W + (size_t)row * NIN); // 8 KB row, lane-coalesced float4

    // Issue ALL weight loads first: 8 x global_load_dwordx4 nt, 8 KB in flight.
    f4 w[8];
    #pragma unroll
    for (int j = 0; j < 8; ++j)
        w[j] = __builtin_nontemporal_load(&w4[j * 64 + lane]);

    // Per-lane gate nibble for each float4 (x is L2-hot: 2 KB reused by 2048 rows).
    unsigned int g[8];
    if (x_is_float) {
        const f4* xf = (const f4*)X + (size_t)d * (NIN / 4);
        #pragma unroll
        for (int j = 0; j < 8; ++j) {
            const f4 xv = xf[j * 64 + lane];
            g[j] = (unsigned)(xv.x != 0.0f)        | ((unsigned)(xv.y != 0.0f) << 1)
                 | ((unsigned)(xv.z != 0.0f) << 2) | ((unsigned)(xv.w != 0.0f) << 3);
        }
    } else if (x_is_bytes) {
        const unsigned int* x4 = (const unsigned int*)(X + (size_t)d * NIN);
        #pragma unroll
        for (int j = 0; j < 8; ++j) {
            const unsigned int xb = x4[j * 64 + lane];   // 4 bool bytes
            g[j] = ((xb & 0x000000ffu) ? 1u : 0u) | ((xb & 0x0000ff00u) ? 2u : 0u)
                 | ((xb & 0x00ff0000u) ? 4u : 0u) | ((xb & 0xff000000u) ? 8u : 0u);
        }
    } else {
        const int* xi = (const int*)X + (size_t)d * NIN;
        #pragma unroll
        for (int j = 0; j < 8; ++j) {
            const int i4 = (j * 64 + lane) * 4;
            g[j] = (xi[i4+0] ? 1u : 0u) | (xi[i4+1] ? 2u : 0u)
                 | (xi[i4+2] ? 4u : 0u) | (xi[i4+3] ? 8u : 0u);
        }
    }

    float acc = 0.0f;
    #pragma unroll
    for (int j = 0; j < 8; ++j) {
        acc += (g[j] & 1u) ? w[j].x : 0.0f;
        acc += (g[j] & 2u) ? w[j].y : 0.0f;
        acc += (g[j] & 4u) ? w[j].z : 0.0f;
        acc += (g[j] & 8u) ? w[j].w : 0.0f;
    }

    // wave-64 reduction; sums are exact small integers in fp32 -> order-independent
    #pragma unroll
    for (int off = 32; off > 0; off >>= 1)
        acc += __shfl_down(acc, off, 64);

    if (lane == 0)
        out[row] = (acc > B[row]) ? 1.0f : 0.0f;
}

extern "C" void kernel_launch(void* const* d_in, const int* in_sizes, int n_in,
                              void* d_out, int out_size, void* d_ws, size_t ws_size,
                              hipStream_t stream) {
    const float*         W = (const float*)d_in[0];
    const unsigned char* X = (const unsigned char*)d_in[1];
    const float*         B = (const float*)d_in[2];
    float*               O = (float*)d_out;

    const int rows = NDIR * NOUT;                      // 131072
    binlin_kernel<<<dim3(rows / 4), dim3(256), 0, stream>>>(W, X, B, O);
}